// Round 13
// baseline (222.417 us; speedup 1.0000x reference)
//
#include <hip/hip_runtime.h>
#include <hip/hip_bf16.h>

#define NQ 2048
#define NB 2

typedef unsigned short u16;
typedef unsigned int u32;
typedef _Float16 f16;
typedef __attribute__((ext_vector_type(8))) _Float16 half8;
typedef __attribute__((ext_vector_type(2))) __fp16 fp16x2;
typedef __attribute__((ext_vector_type(4))) float f32x4;
typedef __attribute__((ext_vector_type(2))) unsigned int u32x2;

#define MFMAH(A, B, C) __builtin_amdgcn_mfma_f32_16x16x32_f16(A, B, C, 0, 0, 0)

__device__ __forceinline__ u16 f2h(float x) {
    f16 h = (f16)x;                 // v_cvt_f16_f32 (RNE)
    return *(u16*)&h;
}
__device__ __forceinline__ float h2f(u16 u) {
    f16 h = *(f16*)&u;
    return (float)h;
}
// packed f32x2 -> fp16x2 (v_cvt_pkrtz_f16_f32), returned as u32
__device__ __forceinline__ u32 pk_h2(float a, float b) {
    union { fp16x2 v; u32 u; } c;
    c.v = __builtin_amdgcn_cvt_pkrtz(a, b);
    return c.u;
}
// raw v_exp_f32 (2^x)
__device__ __forceinline__ float fexp2(float x) {
#if __has_builtin(__builtin_amdgcn_exp2f)
    return __builtin_amdgcn_exp2f(x);
#else
    return exp2f(x);
#endif
}
// async global->LDS DMA, 16B/lane; lds dest is wave-uniform base + lane*16
__device__ __forceinline__ void glds16(const u16* g, u16* l) {
    typedef const __attribute__((address_space(1))) u16 gu16;
    typedef __attribute__((address_space(3))) u16 lu16;
    __builtin_amdgcn_global_load_lds((gu16*)g, (lu16*)l, 16, 0, 0);
}
// counted vmcnt wait (compile-time N)
template <int N> __device__ __forceinline__ void waitvm() {
    if constexpr (N == 0) asm volatile("s_waitcnt vmcnt(0)" ::: "memory");
    else if constexpr (N == 3) asm volatile("s_waitcnt vmcnt(3)" ::: "memory");
    else if constexpr (N == 4) asm volatile("s_waitcnt vmcnt(4)" ::: "memory");
    else static_assert(N == 0 || N == 3 || N == 4, "add case");
}
// VALU cross-lane swaps (gfx950): a/b both updated.
__device__ __forceinline__ void pl32swap(u32& a, u32& b) {
#if __has_builtin(__builtin_amdgcn_permlane32_swap)
    u32x2 r = __builtin_amdgcn_permlane32_swap(a, b, false, false);
    a = r[0]; b = r[1];
#else
    asm volatile("v_permlane32_swap_b32 %0, %1" : "+v"(a), "+v"(b));
#endif
}
__device__ __forceinline__ void pl16swap(u32& a, u32& b) {
#if __has_builtin(__builtin_amdgcn_permlane16_swap)
    u32x2 r = __builtin_amdgcn_permlane16_swap(a, b, false, false);
    a = r[0]; b = r[1];
#else
    asm volatile("v_permlane16_swap_b32 %0, %1" : "+v"(a), "+v"(b));
#endif
}

// q-scale: 1/sqrt(64) * log2(e), so attention scores land in log2 domain
#define QSCALE 0.18033688011112042f

// ============ fused prep: merged weights + x cast + bias pack ============
// blocks [0,4096): W + dB@dW -> fp16 (rows 0..3071 = q,k,v; 3072.. = o)
// blocks [4096,8192): x -> fp16
// blocks [8192,8208): bias pack
__global__ __launch_bounds__(256) void prep(
    const float* __restrict__ w0, const float* __restrict__ dw0, const float* __restrict__ db0,
    const float* __restrict__ w1, const float* __restrict__ dw1, const float* __restrict__ db1,
    const float* __restrict__ w2, const float* __restrict__ dw2, const float* __restrict__ db2,
    const float* __restrict__ w3, const float* __restrict__ dw3, const float* __restrict__ db3,
    u16* __restrict__ Wf,
    const float* __restrict__ x, u16* __restrict__ xf,
    const float* __restrict__ b0, const float* __restrict__ b1,
    const float* __restrict__ b2, const float* __restrict__ b3,
    float* __restrict__ ball) {
    const int bid = blockIdx.x;
    if (bid >= 8192) {
        int t = (bid - 8192) * 256 + threadIdx.x;   // 4096
        int which = t >> 10;
        const float* B = (which == 0) ? b0 : (which == 1) ? b1 : (which == 2) ? b2 : b3;
        float v = B[t & 1023];
        if (which == 0) v *= QSCALE;
        ball[t] = v;
        return;
    }
    if (bid >= 4096) {
        int i4 = ((bid - 4096) * 256 + threadIdx.x) * 4;
        float4 v = *(const float4*)&x[i4];
        *(uint2*)&xf[i4] = make_uint2(pk_h2(v.x, v.y), pk_h2(v.z, v.w));
        return;
    }
    int i4 = (bid * 256 + threadIdx.x) * 4;   // over 4096*1024
    int row = i4 >> 10, col = i4 & 1023;
    int which = row >> 10, lr = row & 1023;
    const float* W  = (which == 0) ? w0  : (which == 1) ? w1  : (which == 2) ? w2  : w3;
    const float* dW = (which == 0) ? dw0 : (which == 1) ? dw1 : (which == 2) ? dw2 : dw3;
    const float* dB = (which == 0) ? db0 : (which == 1) ? db1 : (which == 2) ? db2 : db3;
    float4 acc = *(const float4*)&W[lr * 1024 + col];
#pragma unroll
    for (int r = 0; r < 5; ++r) {
        float s = dB[lr * 5 + r];                    // block-uniform
        float4 w4 = *(const float4*)&dW[r * 1024 + col];
        acc.x += s * w4.x; acc.y += s * w4.y;
        acc.z += s * w4.z; acc.w += s * w4.w;
    }
    if (which == 0) { acc.x *= QSCALE; acc.y *= QSCALE; acc.z *= QSCALE; acc.w *= QSCALE; }
    ushort4 o = make_ushort4(f2h(acc.x), f2h(acc.y), f2h(acc.z), f2h(acc.w));
    *(ushort4*)&Wf[i4] = o;
}

// ============ fp16 GEMM: C[4096][N] = A @ B^T + bias ============
// TM x 128 tile, BK=32 K-steps. 3-BUFFER, 2-AHEAD pipeline with COUNTED
// vmcnt (T4, proven +7.5us in R8). Packed [row][32] layout, XOR chunk
// swizzle both-sides. If VtOut: columns >= 2048 store TRANSPOSED.
template <int TM>
__global__ __launch_bounds__(256) void gemm_f16(
    const u16* __restrict__ Af, const u16* __restrict__ Bf,
    const float* __restrict__ bias,
    float* __restrict__ Cf, u16* __restrict__ Cb, int ldc,
    u16* __restrict__ VtOut) {
    constexpr int MI = TM / 32;               // m-subtiles per wave
    constexpr int LPS = TM / 64 + 2;          // glds16 issued per wave per step
    __shared__ u16 As[3][TM * 32];            // [buf][row*32]
    __shared__ u16 Bs[3][128 * 32];
    const int tid = threadIdx.x;
    const int wid = tid >> 6, lane = tid & 63;
    const int ln = lane & 15, quad = lane >> 4;
    const int bm = blockIdx.y * TM, bn = blockIdx.x * 128;
    const int wm = (wid >> 1) * (TM / 2), wn = (wid & 1) * 64;
    const int lrow = lane >> 2;               // DMA: row within 16-row group
    const int schunk = ((lane & 3) ^ ((lrow >> 1) & 3)) * 8;
    const int kswz = (quad ^ ((ln >> 1) & 3)) * 8;

    f32x4 acc[MI][4];
#pragma unroll
    for (int i = 0; i < MI; ++i)
#pragma unroll
        for (int j = 0; j < 4; ++j) acc[i][j] = (f32x4){0.f, 0.f, 0.f, 0.f};

    auto GSTAGE = [&](int s, int bu) {        // stage K-step s (cols s*32..)
#pragma unroll
        for (int p = 0; p < TM / 64; ++p) {
            int r = p * 64 + wid * 16;
            glds16(&Af[(bm + r + lrow) * 1024 + s * 32 + schunk], &As[bu][r * 32]);
        }
#pragma unroll
        for (int p = 0; p < 2; ++p) {
            int r = p * 64 + wid * 16;
            glds16(&Bf[(bn + r + lrow) * 1024 + s * 32 + schunk], &Bs[bu][r * 32]);
        }
    };

    auto COMPUTE = [&](int bu) {
        half8 a[MI], b[4];
#pragma unroll
        for (int j = 0; j < 4; ++j)
            b[j] = *(const half8*)&Bs[bu][(wn + j * 16 + ln) * 32 + kswz];
#pragma unroll
        for (int i = 0; i < MI; ++i)
            a[i] = *(const half8*)&As[bu][(wm + i * 16 + ln) * 32 + kswz];
#pragma unroll
        for (int i = 0; i < MI; ++i)
#pragma unroll
            for (int j = 0; j < 4; ++j)
                acc[i][j] = MFMAH(a[i], b[j], acc[i][j]);
    };

    // prologue: tiles 0,1 staged; wait only tile 0 (tile 1 in flight)
    GSTAGE(0, 0);
    GSTAGE(1, 1);
    waitvm<LPS>();
    __syncthreads();

    // 32 K-steps total; tile t lives in buf t%3. Main loop covers t=0..29.
    for (int s = 0; s < 30; s += 3) {
        GSTAGE(s + 2, 2); COMPUTE(0); waitvm<LPS>(); __syncthreads();
        GSTAGE(s + 3, 0); COMPUTE(1); waitvm<LPS>(); __syncthreads();
        GSTAGE(s + 4, 1); COMPUTE(2); waitvm<LPS>(); __syncthreads();
    }
    // tail: tiles 30 (buf0, already landed), 31 (buf1, drain)
    COMPUTE(0);
    waitvm<0>();
    __syncthreads();
    COMPUTE(1);

    if (VtOut && bn >= 2048) {
        // transposed store: VtOut[d][seq]; lane holds 4 consecutive seq rows.
#pragma unroll
        for (int i = 0; i < MI; ++i)
#pragma unroll
            for (int j = 0; j < 4; ++j) {
                int col = bn + wn + j * 16 + ln;
                float bv = bias[col];
                int colV = col - 2048;
                int row0 = bm + wm + i * 16 + quad * 4;
                ushort4 pk = make_ushort4(f2h(acc[i][j][0] + bv), f2h(acc[i][j][1] + bv),
                                          f2h(acc[i][j][2] + bv), f2h(acc[i][j][3] + bv));
                *(ushort4*)&VtOut[colV * 4096 + row0] = pk;
            }
        return;
    }

#pragma unroll
    for (int i = 0; i < MI; ++i)
#pragma unroll
        for (int j = 0; j < 4; ++j) {
            int col = bn + wn + j * 16 + ln;
            float bv = bias[col];
#pragma unroll
            for (int r = 0; r < 4; ++r) {
                int row = bm + wm + i * 16 + quad * 4 + r;
                float v = acc[i][j][r] + bv;
                if (Cb) Cb[row * ldc + col] = f2h(v);
                else    Cf[row * ldc + col] = v;
            }
        }
}

// ============ flash attention, fp16 MFMA, split-KV x2 ============
// Each (qt,h,b) q-tile is processed by TWO blocks, each owning a disjoint
// half of the keys -> 1024 blocks x 4 waves = 16 waves/CU (vs 8), no
// redundant K/V staging. Blocks write NORMALIZED fp16 partials (O_h / s_h,
// values O(1) -> fp16-safe) + PER-HEAD row sums; combine computes the
// weighted merge w0*P0 + w1*P1 with w_h = s_h/(s0+s1) PER (q,head).
// (R12 bug: svec was indexed [hb][q] only -- all 16 head-blocks race-wrote
// one slot, so combine used a random head's denominators -> absmax 3.7e-2.
// The softmax denominator is per-(q,head); svec is now [hb][q][head].)
// ZERO workspace growth: half0 -> AO (its final home); half1 -> QKV's dead
// V-third (cols 2048..3071 -- disjoint from flash's Q/K reads, cols 0..2047);
// svec (512KB) -> dead q-weight rows of Wf (6MB dead after QKV GEMM).
// R5 2-buffer schedule, packed [row][32] chunk-swizzled LDS (0 conflicts),
// log2-domain scores, cvt_pkrtz + permlane butterfly, ones-MFMA row sums.
__global__ __launch_bounds__(256) void flash_f16(
    const u16* __restrict__ QKV, const u16* __restrict__ Vt,
    u16* __restrict__ P1, u16* __restrict__ AO, float* __restrict__ svec) {
    __shared__ u16 Ks[2][2][64 * 32];   // [buf][d-half][key row][32], chunk-swizzled
    __shared__ u16 Vs[2][2][64 * 32];   // [buf][key-half][d row][32], chunk-swizzled

    const int tid = threadIdx.x;
    const int wid = tid >> 6, lane = tid & 63;
    const int ln = lane & 15, quad = lane >> 4;
    const int qt = blockIdx.x, h = blockIdx.y;
    const int b = blockIdx.z >> 1, hb = blockIdx.z & 1;   // batch, key-half
    const int rowbase = b * NQ;
    const int keybase = hb * (NQ / 2);
    const int col0 = h * 64;
    const int q0 = rowbase + qt * 128 + wid * 32;
    const int lrow = lane >> 2;          // DMA: row within 16-row group
    const int kchunk = ((lane & 3) ^ ((lrow >> 1) & 3)) * 8;
    const int kswz = (quad ^ ((ln >> 1) & 3)) * 8;

    const half8 ones = {(f16)1, (f16)1, (f16)1, (f16)1,
                        (f16)1, (f16)1, (f16)1, (f16)1};

    // Q fragments (B-operand: lane ln = q-row q0+mi*16+ln, k = kc*32+quad*8+j)
    half8 qf[2][2];
#pragma unroll
    for (int mi = 0; mi < 2; ++mi)
#pragma unroll
        for (int kc = 0; kc < 2; ++kc)
            qf[mi][kc] = *(const half8*)&QKV[(q0 + mi * 16 + ln) * 3072 + col0 +
                                             kc * 32 + quad * 8];

    f32x4 accO[4][2];    // [a: d-subtile][mi], element (d=a*16+quad*4+r, q=mi*16+ln)
    f32x4 accS[2];       // row sums, col = q = ln
#pragma unroll
    for (int mi = 0; mi < 2; ++mi) {
        accS[mi] = (f32x4){0.f, 0.f, 0.f, 0.f};
#pragma unroll
        for (int a = 0; a < 4; ++a) accO[a][mi] = (f32x4){0.f, 0.f, 0.f, 0.f};
    }

    const int NT = (NQ / 2) / 64;   // 16 key-tiles of 64 in this half
    // DMA per-lane global bases (16 rows x 64B per glds16 call per wave)
    const u16* Kg = QKV + (rowbase + keybase + wid * 16 + lrow) * 3072 + 1024 +
                    col0 + kchunk;
    const u16* Vg = Vt + (col0 + wid * 16 + lrow) * 4096 + rowbase + keybase + kchunk;

#define STAGEK(kt2, bu)                                        \
    {                                                          \
        const u16* kg_ = Kg + (kt2) * (64 * 3072);             \
        glds16(kg_,      &Ks[bu][0][wid * 512]);               \
        glds16(kg_ + 32, &Ks[bu][1][wid * 512]);               \
    }
#define STAGEV(kt2, bu)                                        \
    {                                                          \
        const u16* vg_ = Vg + (kt2) * 64;                      \
        glds16(vg_,      &Vs[bu][0][wid * 512]);               \
        glds16(vg_ + 32, &Vs[bu][1][wid * 512]);               \
    }

    // QK^T from Ks[kb] -> exp -> butterfly -> pf (B-operand layout) + rowsum.
    auto qk_exp = [&](int kb, half8 (&pf)[2][2]) {
        // S^T = K @ Q^T : element (key = a*16+quad*4+r, q = mi*16+ln)
        f32x4 s[4][2];
        __builtin_amdgcn_s_setprio(1);
#pragma unroll
        for (int a = 0; a < 4; ++a) {
            half8 kf0 = *(const half8*)&Ks[kb][0][(a * 16 + ln) * 32 + kswz];
            half8 kf1 = *(const half8*)&Ks[kb][1][(a * 16 + ln) * 32 + kswz];
#pragma unroll
            for (int mi = 0; mi < 2; ++mi) {
                f32x4 t = (f32x4){0.f, 0.f, 0.f, 0.f};
                t = MFMAH(kf0, qf[mi][0], t);
                t = MFMAH(kf1, qf[mi][1], t);
                s[a][mi] = t;
            }
        }
        __builtin_amdgcn_s_setprio(0);
        // p = 2^s, pack to fp16 pairs, register butterfly to B-operand layout:
        // pf[mi][kc] element j = P[key = kc*32 + quad*8 + j][q = mi*16+ln].
#pragma unroll
        for (int mi = 0; mi < 2; ++mi)
#pragma unroll
            for (int kc = 0; kc < 2; ++kc) {
                u32 c0 = pk_h2(fexp2(s[2 * kc][mi][0]), fexp2(s[2 * kc][mi][1]));
                u32 c1 = pk_h2(fexp2(s[2 * kc][mi][2]), fexp2(s[2 * kc][mi][3]));
                u32 c2 = pk_h2(fexp2(s[2 * kc + 1][mi][0]), fexp2(s[2 * kc + 1][mi][1]));
                u32 c3 = pk_h2(fexp2(s[2 * kc + 1][mi][2]), fexp2(s[2 * kc + 1][mi][3]));
                pl32swap(c0, c2);
                pl32swap(c1, c3);
                pl16swap(c0, c2);
                pl16swap(c1, c3);
                union { u32 u[4]; half8 h; } pu;
                pu.u[0] = c0; pu.u[1] = c1; pu.u[2] = c2; pu.u[3] = c3;
                pf[mi][kc] = pu.h;
                accS[mi] = MFMAH(ones, pf[mi][kc], accS[mi]);   // row sums
            }
    };

    // O^T += V^T @ P^T from Vs[vb] : element (d = a*16+quad*4+r, q = mi*16+ln)
    auto pv = [&](const half8 (&pf)[2][2], int vb) {
        __builtin_amdgcn_s_setprio(1);
#pragma unroll
        for (int a = 0; a < 4; ++a) {
            half8 vf0 = *(const half8*)&Vs[vb][0][(a * 16 + ln) * 32 + kswz];
            half8 vf1 = *(const half8*)&Vs[vb][1][(a * 16 + ln) * 32 + kswz];
#pragma unroll
            for (int mi = 0; mi < 2; ++mi) {
                accO[a][mi] = MFMAH(vf0, pf[mi][0], accO[a][mi]);
                accO[a][mi] = MFMAH(vf1, pf[mi][1], accO[a][mi]);
            }
        }
        __builtin_amdgcn_s_setprio(0);
    };

    half8 pfA[2][2], pfB[2][2];

    // prologue: tile 0 staged, pfA = P(0); K(1) staged for first phase
    STAGEK(0, 0);
    STAGEV(0, 0);
    asm volatile("s_waitcnt vmcnt(0)" ::: "memory");
    __syncthreads();
    STAGEK(1, 1);
    qk_exp(0, pfA);
    asm volatile("s_waitcnt vmcnt(0)" ::: "memory");
    __syncthreads();

    // main loop: branch-free even/odd phases, 2 tiles/iteration.
    // phase A: writes Ks[0],Vs[1]; reads Ks[1](QK kt+1), Vs[0](PV kt).
    // phase B: writes Ks[1],Vs[0]; reads Ks[0](QK kt+2), Vs[1](PV kt+1).
    for (int kt = 0; kt < NT - 2; kt += 2) {
        STAGEK(kt + 2, 0);
        STAGEV(kt + 1, 1);
        qk_exp(1, pfB);          // tile kt+1 (exp overlaps PV below)
        pv(pfA, 0);              // tile kt
        asm volatile("s_waitcnt vmcnt(0)" ::: "memory");
        __syncthreads();

        STAGEK(kt + 3, 1);
        STAGEV(kt + 2, 0);
        qk_exp(0, pfA);          // tile kt+2
        pv(pfB, 1);              // tile kt+1
        asm volatile("s_waitcnt vmcnt(0)" ::: "memory");
        __syncthreads();
    }
    // tail: tiles NT-2, NT-1 (state: pfA = P(NT-2), Ks[1]=K(NT-1), Vs[0]=V(NT-2))
    STAGEV(NT - 1, 1);
    qk_exp(1, pfB);              // tile NT-1
    pv(pfA, 0);                  // tile NT-2
    asm volatile("s_waitcnt vmcnt(0)" ::: "memory");
    __syncthreads();
    pv(pfB, 1);                  // tile NT-1
#undef STAGEK
#undef STAGEV

    // epilogue: per-half NORMALIZED fp16 partials + PER-HEAD row sums.
    // half0 -> AO[q][0..1023] (ld 1024); half1 -> QKV v-slot (ld 3072, +2048).
    u16* dst = hb ? (P1 + 2048) : AO;
    const int ldd = hb ? 3072 : 1024;
#pragma unroll
    for (int mi = 0; mi < 2; ++mi) {
        float inv = 1.f / accS[mi][0];
        int q = q0 + mi * 16 + ln;
        if (quad == 0) svec[((hb * 4096 + q) << 4) + h] = accS[mi][0];
#pragma unroll
        for (int a = 0; a < 4; ++a) {
            ushort4 pk = make_ushort4(f2h(accO[a][mi][0] * inv),
                                      f2h(accO[a][mi][1] * inv),
                                      f2h(accO[a][mi][2] * inv),
                                      f2h(accO[a][mi][3] * inv));
            *(ushort4*)&dst[(size_t)q * ldd + col0 + a * 16 + quad * 4] = pk;
        }
    }
}

// ============ combine: AO = w0*P0 + w1*P1, w_h = s_h/(s0+s1) per (q,head) ============
__global__ __launch_bounds__(256) void combine(
    const u16* __restrict__ QKV, const float* __restrict__ svec,
    u16* __restrict__ AO) {
    const int q = blockIdx.x;            // 4096 rows
    const int c = threadIdx.x * 4;       // 1024 features / 256 threads
    const int hh = c >> 6;               // head of this feature chunk
    const float s0 = svec[(q << 4) + hh];
    const float s1 = svec[((4096 + q) << 4) + hh];
    const float r = 1.f / (s0 + s1);
    const float w0 = s0 * r, w1 = s1 * r;
    ushort4 a0 = *(const ushort4*)&AO[(size_t)q * 1024 + c];
    ushort4 a1 = *(const ushort4*)&QKV[(size_t)q * 3072 + 2048 + c];
    ushort4 pk = make_ushort4(f2h(h2f(a0.x) * w0 + h2f(a1.x) * w1),
                              f2h(h2f(a0.y) * w0 + h2f(a1.y) * w1),
                              f2h(h2f(a0.z) * w0 + h2f(a1.z) * w1),
                              f2h(h2f(a0.w) * w0 + h2f(a1.w) * w1));
    *(ushort4*)&AO[(size_t)q * 1024 + c] = pk;
}

// ============ launch ============
extern "C" void kernel_launch(void* const* d_in, const int* in_sizes, int n_in,
                              void* d_out, int out_size, void* d_ws, size_t ws_size,
                              hipStream_t stream) {
    const float* x = (const float*)d_in[0];
    const float* w[4]  = {(const float*)d_in[1],  (const float*)d_in[5],
                          (const float*)d_in[9],  (const float*)d_in[13]};
    const float* bv[4] = {(const float*)d_in[2],  (const float*)d_in[6],
                          (const float*)d_in[10], (const float*)d_in[14]};
    const float* dw[4] = {(const float*)d_in[3],  (const float*)d_in[7],
                          (const float*)d_in[11], (const float*)d_in[15]};
    const float* db[4] = {(const float*)d_in[4],  (const float*)d_in[8],
                          (const float*)d_in[12], (const float*)d_in[16]};

    u16* p = (u16*)d_ws;
    u16* Wf  = p; p += 4096 * 1024;
    u16* xf  = p; p += 4096 * 1024;
    u16* QKV = p; p += 4096 * 3072;   // V third: dead until flash, then P1
    u16* Vt  = p; p += 1024 * 4096;
    float* ball = (float*)p;          // 4096 floats
    // AO aliases xf: x is dead after the QKV GEMM completes (same stream).
    u16* AO = xf;
    // svec aliases Wf's q-weight rows (dead after the QKV GEMM; O-GEMM reads
    // only Wf + 3072*1024). 2*4096*16 floats = 512 KB << 6 MB dead region.
    float* svec = (float*)Wf;

    // fused prep: merged weights + x cast + bias pack
    prep<<<8208, 256, 0, stream>>>(w[0], dw[0], db[0], w[1], dw[1], db[1],
                                   w[2], dw[2], db[2], w[3], dw[3], db[3], Wf,
                                   x, xf,
                                   bv[0], bv[1], bv[2], bv[3], ball);

    // fused q,k,v projection: q,k -> QKV fp16 row-major; v -> Vt transposed
    gemm_f16<128><<<dim3(24, 32), 256, 0, stream>>>(xf, Wf, ball,
                                                    nullptr, QKV, 3072, Vt);

    // split-KV flash: z = batch*2 + key-half -> 1024 blocks (16 waves/CU)
    flash_f16<<<dim3(NQ / 128, 16, NB * 2), 256, 0, stream>>>(QKV, Vt, QKV, AO, svec);
    combine<<<4096, 256, 0, stream>>>(QKV, svec, AO);

    // o projection: fp32 out, TM=64 -> 512 blocks (2 blocks/CU)
    gemm_f16<64><<<dim3(8, 64), 256, 0, stream>>>(AO, Wf + 3072 * 1024,
                                                  ball + 3072, (float*)d_out, nullptr, 1024,
                                                  nullptr);
}

// Round 14
// 208.700 us; speedup vs baseline: 1.0657x; 1.0657x over previous
//
#include <hip/hip_runtime.h>
#include <hip/hip_bf16.h>

#define NQ 2048
#define NB 2

typedef unsigned short u16;
typedef unsigned int u32;
typedef _Float16 f16;
typedef __attribute__((ext_vector_type(8))) _Float16 half8;
typedef __attribute__((ext_vector_type(2))) __fp16 fp16x2;
typedef __attribute__((ext_vector_type(4))) float f32x4;
typedef __attribute__((ext_vector_type(2))) unsigned int u32x2;

#define MFMAH(A, B, C) __builtin_amdgcn_mfma_f32_16x16x32_f16(A, B, C, 0, 0, 0)

__device__ __forceinline__ u16 f2h(float x) {
    f16 h = (f16)x;                 // v_cvt_f16_f32 (RNE)
    return *(u16*)&h;
}
// packed f32x2 -> fp16x2 (v_cvt_pkrtz_f16_f32), returned as u32
__device__ __forceinline__ u32 pk_h2(float a, float b) {
    union { fp16x2 v; u32 u; } c;
    c.v = __builtin_amdgcn_cvt_pkrtz(a, b);
    return c.u;
}
// raw v_exp_f32 (2^x)
__device__ __forceinline__ float fexp2(float x) {
#if __has_builtin(__builtin_amdgcn_exp2f)
    return __builtin_amdgcn_exp2f(x);
#else
    return exp2f(x);
#endif
}
// async global->LDS DMA, 16B/lane; lds dest is wave-uniform base + lane*16
__device__ __forceinline__ void glds16(const u16* g, u16* l) {
    typedef const __attribute__((address_space(1))) u16 gu16;
    typedef __attribute__((address_space(3))) u16 lu16;
    __builtin_amdgcn_global_load_lds((gu16*)g, (lu16*)l, 16, 0, 0);
}
// counted vmcnt wait (compile-time N)
template <int N> __device__ __forceinline__ void waitvm() {
    if constexpr (N == 0) asm volatile("s_waitcnt vmcnt(0)" ::: "memory");
    else if constexpr (N == 2) asm volatile("s_waitcnt vmcnt(2)" ::: "memory");
    else if constexpr (N == 3) asm volatile("s_waitcnt vmcnt(3)" ::: "memory");
    else if constexpr (N == 4) asm volatile("s_waitcnt vmcnt(4)" ::: "memory");
    else if constexpr (N == 6) asm volatile("s_waitcnt vmcnt(6)" ::: "memory");
    else static_assert(N == 0 || N == 2 || N == 3 || N == 4 || N == 6, "add case");
}
// VALU cross-lane swaps (gfx950): a/b both updated.
__device__ __forceinline__ void pl32swap(u32& a, u32& b) {
#if __has_builtin(__builtin_amdgcn_permlane32_swap)
    u32x2 r = __builtin_amdgcn_permlane32_swap(a, b, false, false);
    a = r[0]; b = r[1];
#else
    asm volatile("v_permlane32_swap_b32 %0, %1" : "+v"(a), "+v"(b));
#endif
}
__device__ __forceinline__ void pl16swap(u32& a, u32& b) {
#if __has_builtin(__builtin_amdgcn_permlane16_swap)
    u32x2 r = __builtin_amdgcn_permlane16_swap(a, b, false, false);
    a = r[0]; b = r[1];
#else
    asm volatile("v_permlane16_swap_b32 %0, %1" : "+v"(a), "+v"(b));
#endif
}

// q-scale: 1/sqrt(64) * log2(e), so attention scores land in log2 domain
#define QSCALE 0.18033688011112042f

// ============ fused prep: merged weights + x cast + bias pack ============
// blocks [0,4096): W + dB@dW -> fp16 (rows 0..3071 = q,k,v; 3072.. = o)
// blocks [4096,8192): x -> fp16
// blocks [8192,8208): bias pack
__global__ __launch_bounds__(256) void prep(
    const float* __restrict__ w0, const float* __restrict__ dw0, const float* __restrict__ db0,
    const float* __restrict__ w1, const float* __restrict__ dw1, const float* __restrict__ db1,
    const float* __restrict__ w2, const float* __restrict__ dw2, const float* __restrict__ db2,
    const float* __restrict__ w3, const float* __restrict__ dw3, const float* __restrict__ db3,
    u16* __restrict__ Wf,
    const float* __restrict__ x, u16* __restrict__ xf,
    const float* __restrict__ b0, const float* __restrict__ b1,
    const float* __restrict__ b2, const float* __restrict__ b3,
    float* __restrict__ ball) {
    const int bid = blockIdx.x;
    if (bid >= 8192) {
        int t = (bid - 8192) * 256 + threadIdx.x;   // 4096
        int which = t >> 10;
        const float* B = (which == 0) ? b0 : (which == 1) ? b1 : (which == 2) ? b2 : b3;
        float v = B[t & 1023];
        if (which == 0) v *= QSCALE;
        ball[t] = v;
        return;
    }
    if (bid >= 4096) {
        int i4 = ((bid - 4096) * 256 + threadIdx.x) * 4;
        float4 v = *(const float4*)&x[i4];
        *(uint2*)&xf[i4] = make_uint2(pk_h2(v.x, v.y), pk_h2(v.z, v.w));
        return;
    }
    int i4 = (bid * 256 + threadIdx.x) * 4;   // over 4096*1024
    int row = i4 >> 10, col = i4 & 1023;
    int which = row >> 10, lr = row & 1023;
    const float* W  = (which == 0) ? w0  : (which == 1) ? w1  : (which == 2) ? w2  : w3;
    const float* dW = (which == 0) ? dw0 : (which == 1) ? dw1 : (which == 2) ? dw2 : dw3;
    const float* dB = (which == 0) ? db0 : (which == 1) ? db1 : (which == 2) ? db2 : db3;
    float4 acc = *(const float4*)&W[lr * 1024 + col];
#pragma unroll
    for (int r = 0; r < 5; ++r) {
        float s = dB[lr * 5 + r];                    // block-uniform
        float4 w4 = *(const float4*)&dW[r * 1024 + col];
        acc.x += s * w4.x; acc.y += s * w4.y;
        acc.z += s * w4.z; acc.w += s * w4.w;
    }
    if (which == 0) { acc.x *= QSCALE; acc.y *= QSCALE; acc.z *= QSCALE; acc.w *= QSCALE; }
    ushort4 o = make_ushort4(f2h(acc.x), f2h(acc.y), f2h(acc.z), f2h(acc.w));
    *(ushort4*)&Wf[i4] = o;
}

// ============ fp16 GEMM: C[4096][N] = A @ B^T + bias ============
// TM x 128 tile, BK=32 K-steps. 3-BUFFER, 2-AHEAD pipeline with COUNTED
// vmcnt (T4, proven +7.5us in R8). Packed [row][32] layout, XOR chunk
// swizzle both-sides. XCD-AWARE BLOCK SWIZZLE (T1, this round): chunks of
// nwg/8 consecutive tiles per XCD -> consecutive M-tiles (sharing A-panels)
// land on ONE XCD's L2 instead of round-robining across all 8.
// If VtOut: columns >= 2048 store TRANSPOSED.
template <int TM>
__global__ __launch_bounds__(256) void gemm_f16(
    const u16* __restrict__ Af, const u16* __restrict__ Bf,
    const float* __restrict__ bias,
    float* __restrict__ Cf, u16* __restrict__ Cb, int ldc,
    u16* __restrict__ VtOut) {
    constexpr int MI = TM / 32;               // m-subtiles per wave
    constexpr int LPS = TM / 64 + 2;          // glds16 issued per wave per step
    __shared__ u16 As[3][TM * 32];            // [buf][row*32]
    __shared__ u16 Bs[3][128 * 32];
    const int tid = threadIdx.x;
    const int wid = tid >> 6, lane = tid & 63;
    const int ln = lane & 15, quad = lane >> 4;
    // XCD swizzle: bijective (grid totals 768 / 512, both % 8 == 0)
    const int nwg = gridDim.x * gridDim.y;
    const int lin = blockIdx.y * gridDim.x + blockIdx.x;
    const int tile = (lin & 7) * (nwg >> 3) + (lin >> 3);
    const int bxs = tile % gridDim.x, bys = tile / gridDim.x;
    const int bm = bys * TM, bn = bxs * 128;
    const int wm = (wid >> 1) * (TM / 2), wn = (wid & 1) * 64;
    const int lrow = lane >> 2;               // DMA: row within 16-row group
    const int schunk = ((lane & 3) ^ ((lrow >> 1) & 3)) * 8;
    const int kswz = (quad ^ ((ln >> 1) & 3)) * 8;

    f32x4 acc[MI][4];
#pragma unroll
    for (int i = 0; i < MI; ++i)
#pragma unroll
        for (int j = 0; j < 4; ++j) acc[i][j] = (f32x4){0.f, 0.f, 0.f, 0.f};

    auto GSTAGE = [&](int s, int bu) {        // stage K-step s (cols s*32..)
#pragma unroll
        for (int p = 0; p < TM / 64; ++p) {
            int r = p * 64 + wid * 16;
            glds16(&Af[(bm + r + lrow) * 1024 + s * 32 + schunk], &As[bu][r * 32]);
        }
#pragma unroll
        for (int p = 0; p < 2; ++p) {
            int r = p * 64 + wid * 16;
            glds16(&Bf[(bn + r + lrow) * 1024 + s * 32 + schunk], &Bs[bu][r * 32]);
        }
    };

    auto COMPUTE = [&](int bu) {
        half8 a[MI], b[4];
#pragma unroll
        for (int j = 0; j < 4; ++j)
            b[j] = *(const half8*)&Bs[bu][(wn + j * 16 + ln) * 32 + kswz];
#pragma unroll
        for (int i = 0; i < MI; ++i)
            a[i] = *(const half8*)&As[bu][(wm + i * 16 + ln) * 32 + kswz];
#pragma unroll
        for (int i = 0; i < MI; ++i)
#pragma unroll
            for (int j = 0; j < 4; ++j)
                acc[i][j] = MFMAH(a[i], b[j], acc[i][j]);
    };

    // prologue: tiles 0,1 staged; wait only tile 0 (tile 1 in flight)
    GSTAGE(0, 0);
    GSTAGE(1, 1);
    waitvm<LPS>();
    __syncthreads();

    // 32 K-steps total; tile t lives in buf t%3. Main loop covers t=0..29.
    for (int s = 0; s < 30; s += 3) {
        GSTAGE(s + 2, 2); COMPUTE(0); waitvm<LPS>(); __syncthreads();
        GSTAGE(s + 3, 0); COMPUTE(1); waitvm<LPS>(); __syncthreads();
        GSTAGE(s + 4, 1); COMPUTE(2); waitvm<LPS>(); __syncthreads();
    }
    // tail: tiles 30 (buf0, already landed), 31 (buf1, drain)
    COMPUTE(0);
    waitvm<0>();
    __syncthreads();
    COMPUTE(1);

    if (VtOut && bn >= 2048) {
        // transposed store: VtOut[d][seq]; lane holds 4 consecutive seq rows.
#pragma unroll
        for (int i = 0; i < MI; ++i)
#pragma unroll
            for (int j = 0; j < 4; ++j) {
                int col = bn + wn + j * 16 + ln;
                float bv = bias[col];
                int colV = col - 2048;
                int row0 = bm + wm + i * 16 + quad * 4;
                ushort4 pk = make_ushort4(f2h(acc[i][j][0] + bv), f2h(acc[i][j][1] + bv),
                                          f2h(acc[i][j][2] + bv), f2h(acc[i][j][3] + bv));
                *(ushort4*)&VtOut[colV * 4096 + row0] = pk;
            }
        return;
    }

#pragma unroll
    for (int i = 0; i < MI; ++i)
#pragma unroll
        for (int j = 0; j < 4; ++j) {
            int col = bn + wn + j * 16 + ln;
            float bv = bias[col];
#pragma unroll
            for (int r = 0; r < 4; ++r) {
                int row = bm + wm + i * 16 + quad * 4 + r;
                float v = acc[i][j][r] + bv;
                if (Cb) Cb[row * ldc + col] = f2h(v);
                else    Cf[row * ldc + col] = v;
            }
        }
}

// ============ flash attention, fp16 MFMA, transposed S/O ============
// R10 configuration (best measured flash: 52.6us). Block: 4 waves x 32
// q-rows = 128 q of one (b,h). KVBLK=64, THREE LDS buffers, COUNTED vmcnt:
// phase p stages K(p+3), V(p+2); waits vmcnt(4) (prev phase's loads only)
// while this phase's loads stay in flight across the barrier.
// XCD-AWARE BLOCK SWIZZLE (T1, this round): default x-fastest dispatch
// spreads the 16 qt-blocks sharing one 512KB K/V head across all 8 XCDs
// (8x L2 re-fetch -> 70MB FETCH vs ~24MB ideal). Swizzled chunks of 64
// give each XCD 4 complete heads (2MB, L2-resident), each fetched once.
// Packed [row][32] chunk-swizzled LDS (0 conflicts), log2-domain scores,
// cvt_pkrtz + permlane butterfly, ones-MFMA row sums, setprio.
__global__ __launch_bounds__(256) void flash_f16(
    const u16* __restrict__ QKV, const u16* __restrict__ Vt,
    u16* __restrict__ AO) {
    __shared__ u16 Ks[3][2][64 * 32];   // [buf][d-half][key row][32], chunk-swizzled
    __shared__ u16 Vs[3][2][64 * 32];   // [buf][key-half][d row][32], chunk-swizzled

    const int tid = threadIdx.x;
    const int wid = tid >> 6, lane = tid & 63;
    const int ln = lane & 15, quad = lane >> 4;
    // XCD swizzle over the 512-block grid (16 qt x 16 h x 2 b), bijective.
    const int lin = (blockIdx.z * gridDim.y + blockIdx.y) * gridDim.x + blockIdx.x;
    const int tile = (lin & 7) * 64 + (lin >> 3);
    const int qt = tile & 15, h = (tile >> 4) & 15, b = tile >> 8;
    const int rowbase = b * NQ;
    const int col0 = h * 64;
    const int q0 = rowbase + qt * 128 + wid * 32;
    const int lrow = lane >> 2;          // DMA: row within 16-row group
    const int kchunk = ((lane & 3) ^ ((lrow >> 1) & 3)) * 8;
    const int kswz = (quad ^ ((ln >> 1) & 3)) * 8;

    const half8 ones = {(f16)1, (f16)1, (f16)1, (f16)1,
                        (f16)1, (f16)1, (f16)1, (f16)1};

    // Q fragments (B-operand: lane ln = q-row q0+mi*16+ln, k = kc*32+quad*8+j)
    half8 qf[2][2];
#pragma unroll
    for (int mi = 0; mi < 2; ++mi)
#pragma unroll
        for (int kc = 0; kc < 2; ++kc)
            qf[mi][kc] = *(const half8*)&QKV[(q0 + mi * 16 + ln) * 3072 + col0 +
                                             kc * 32 + quad * 8];

    f32x4 accO[4][2];    // [a: d-subtile][mi], element (d=a*16+quad*4+r, q=mi*16+ln)
    f32x4 accS[2];       // row sums, col = q = ln
#pragma unroll
    for (int mi = 0; mi < 2; ++mi) {
        accS[mi] = (f32x4){0.f, 0.f, 0.f, 0.f};
#pragma unroll
        for (int a = 0; a < 4; ++a) accO[a][mi] = (f32x4){0.f, 0.f, 0.f, 0.f};
    }

    // DMA per-lane global bases (16 rows x 64B per glds16 call per wave)
    const u16* Kg = QKV + (rowbase + wid * 16 + lrow) * 3072 + 1024 + col0 + kchunk;
    const u16* Vg = Vt + (col0 + wid * 16 + lrow) * 4096 + rowbase + kchunk;

#define STAGEK(kt2, bu)                                        \
    {                                                          \
        const u16* kg_ = Kg + (kt2) * (64 * 3072);             \
        glds16(kg_,      &Ks[bu][0][wid * 512]);               \
        glds16(kg_ + 32, &Ks[bu][1][wid * 512]);               \
    }
#define STAGEV(kt2, bu)                                        \
    {                                                          \
        const u16* vg_ = Vg + (kt2) * 64;                      \
        glds16(vg_,      &Vs[bu][0][wid * 512]);               \
        glds16(vg_ + 32, &Vs[bu][1][wid * 512]);               \
    }

    // QK^T from Ks[kb] -> exp -> butterfly -> pf (B-operand layout) + rowsum.
    auto qk_exp = [&](int kb, half8 (&pf)[2][2]) {
        // S^T = K @ Q^T : element (key = a*16+quad*4+r, q = mi*16+ln)
        f32x4 s[4][2];
        __builtin_amdgcn_s_setprio(1);
#pragma unroll
        for (int a = 0; a < 4; ++a) {
            half8 kf0 = *(const half8*)&Ks[kb][0][(a * 16 + ln) * 32 + kswz];
            half8 kf1 = *(const half8*)&Ks[kb][1][(a * 16 + ln) * 32 + kswz];
#pragma unroll
            for (int mi = 0; mi < 2; ++mi) {
                f32x4 t = (f32x4){0.f, 0.f, 0.f, 0.f};
                t = MFMAH(kf0, qf[mi][0], t);
                t = MFMAH(kf1, qf[mi][1], t);
                s[a][mi] = t;
            }
        }
        __builtin_amdgcn_s_setprio(0);
        // p = 2^s, pack to fp16 pairs, register butterfly to B-operand layout:
        // pf[mi][kc] element j = P[key = kc*32 + quad*8 + j][q = mi*16+ln].
#pragma unroll
        for (int mi = 0; mi < 2; ++mi)
#pragma unroll
            for (int kc = 0; kc < 2; ++kc) {
                u32 c0 = pk_h2(fexp2(s[2 * kc][mi][0]), fexp2(s[2 * kc][mi][1]));
                u32 c1 = pk_h2(fexp2(s[2 * kc][mi][2]), fexp2(s[2 * kc][mi][3]));
                u32 c2 = pk_h2(fexp2(s[2 * kc + 1][mi][0]), fexp2(s[2 * kc + 1][mi][1]));
                u32 c3 = pk_h2(fexp2(s[2 * kc + 1][mi][2]), fexp2(s[2 * kc + 1][mi][3]));
                pl32swap(c0, c2);
                pl32swap(c1, c3);
                pl16swap(c0, c2);
                pl16swap(c1, c3);
                union { u32 u[4]; half8 h; } pu;
                pu.u[0] = c0; pu.u[1] = c1; pu.u[2] = c2; pu.u[3] = c3;
                pf[mi][kc] = pu.h;
                accS[mi] = MFMAH(ones, pf[mi][kc], accS[mi]);   // row sums
            }
    };

    // O^T += V^T @ P^T from Vs[vb] : element (d = a*16+quad*4+r, q = mi*16+ln)
    auto pv = [&](const half8 (&pf)[2][2], int vb) {
        __builtin_amdgcn_s_setprio(1);
#pragma unroll
        for (int a = 0; a < 4; ++a) {
            half8 vf0 = *(const half8*)&Vs[vb][0][(a * 16 + ln) * 32 + kswz];
            half8 vf1 = *(const half8*)&Vs[vb][1][(a * 16 + ln) * 32 + kswz];
#pragma unroll
            for (int mi = 0; mi < 2; ++mi) {
                accO[a][mi] = MFMAH(vf0, pf[mi][0], accO[a][mi]);
                accO[a][mi] = MFMAH(vf1, pf[mi][1], accO[a][mi]);
            }
        }
        __builtin_amdgcn_s_setprio(0);
    };

    half8 pfA[2][2], pfB[2][2];

    // prologue: K0,V0,K1,V1,K2 staged (issue order matters for vmcnt).
    STAGEK(0, 0); STAGEV(0, 0);       // 4 loads
    STAGEK(1, 1); STAGEV(1, 1);       // 4
    STAGEK(2, 2);                     // 2  -> 10 outstanding
    waitvm<6>();                      // K0,V0 landed (K1,V1,K2 in flight)
    __syncthreads();
    qk_exp(0, pfA);                   // P(0) from buf0
    waitvm<2>();                      // K1,V1 landed (K2 in flight)
    __syncthreads();

    // main loop: 30 phases, 6-phase unroll (lcm of buf%3 and pf%2).
    // phase p: STAGEK(p+3 -> buf p%3), STAGEV(p+2 -> buf (p+2)%3),
    //          qk(p+1 from buf (p+1)%3 -> pf[(p+1)%2]), pv(p, pf[p%2], buf p%3),
    //          vmcnt(4) [drains PREV phase's loads only], barrier.
    for (int kt = 0; kt < 30; kt += 6) {
        STAGEK(kt + 3, 0); STAGEV(kt + 2, 2);
        qk_exp(1, pfB); pv(pfA, 0);
        waitvm<4>(); __syncthreads();

        STAGEK(kt + 4, 1); STAGEV(kt + 3, 0);
        qk_exp(2, pfA); pv(pfB, 1);
        waitvm<4>(); __syncthreads();

        STAGEK(kt + 5, 2); STAGEV(kt + 4, 1);
        qk_exp(0, pfB); pv(pfA, 2);
        waitvm<4>(); __syncthreads();

        STAGEK(kt + 6, 0); STAGEV(kt + 5, 2);
        qk_exp(1, pfA); pv(pfB, 0);
        waitvm<4>(); __syncthreads();

        STAGEK(kt + 7, 1); STAGEV(kt + 6, 0);
        qk_exp(2, pfB); pv(pfA, 1);
        waitvm<4>(); __syncthreads();

        // p = kt+5: K(p+3) may exceed 31 on the last iteration -> clamp.
        // clamped write lands in buf2 over K(29), which is never read again.
        STAGEK(((kt + 8) > 31 ? 31 : (kt + 8)), 2); STAGEV(kt + 7, 1);
        qk_exp(0, pfA); pv(pfB, 2);
        waitvm<4>(); __syncthreads();
    }
    // tail: phases 30, 31. State: pfA = P(30); K31 in buf1 (landed),
    // V30 in buf0 (landed), V31 in buf1 (in flight).
    qk_exp(1, pfB);                   // P(31)
    pv(pfA, 0);                       // PV(30)
    waitvm<0>();                      // V31 landed
    __syncthreads();
    pv(pfB, 1);                       // PV(31)
#undef STAGEK
#undef STAGEV

    // epilogue: normalize (inv uniform per lane), single fp16 AO, ushort4 stores
#pragma unroll
    for (int mi = 0; mi < 2; ++mi) {
        float inv = 1.f / accS[mi][0];
        int q = q0 + mi * 16 + ln;
#pragma unroll
        for (int a = 0; a < 4; ++a) {
            ushort4 pk = make_ushort4(f2h(accO[a][mi][0] * inv),
                                      f2h(accO[a][mi][1] * inv),
                                      f2h(accO[a][mi][2] * inv),
                                      f2h(accO[a][mi][3] * inv));
            *(ushort4*)&AO[q * 1024 + col0 + a * 16 + quad * 4] = pk;
        }
    }
}

// ============ launch ============
extern "C" void kernel_launch(void* const* d_in, const int* in_sizes, int n_in,
                              void* d_out, int out_size, void* d_ws, size_t ws_size,
                              hipStream_t stream) {
    const float* x = (const float*)d_in[0];
    const float* w[4]  = {(const float*)d_in[1],  (const float*)d_in[5],
                          (const float*)d_in[9],  (const float*)d_in[13]};
    const float* bv[4] = {(const float*)d_in[2],  (const float*)d_in[6],
                          (const float*)d_in[10], (const float*)d_in[14]};
    const float* dw[4] = {(const float*)d_in[3],  (const float*)d_in[7],
                          (const float*)d_in[11], (const float*)d_in[15]};
    const float* db[4] = {(const float*)d_in[4],  (const float*)d_in[8],
                          (const float*)d_in[12], (const float*)d_in[16]};

    u16* p = (u16*)d_ws;
    u16* Wf  = p; p += 4096 * 1024;
    u16* xf  = p; p += 4096 * 1024;
    u16* QKV = p; p += 4096 * 3072;   // V third unused (lives in Vt)
    u16* Vt  = p; p += 1024 * 4096;
    float* ball = (float*)p;          // 4096 floats
    // AO aliases xf: x is dead after the QKV GEMM completes (same stream).
    u16* AO = xf;

    // fused prep: merged weights + x cast + bias pack
    prep<<<8208, 256, 0, stream>>>(w[0], dw[0], db[0], w[1], dw[1], db[1],
                                   w[2], dw[2], db[2], w[3], dw[3], db[3], Wf,
                                   x, xf,
                                   bv[0], bv[1], bv[2], bv[3], ball);

    // fused q,k,v projection: q,k -> QKV fp16 row-major; v -> Vt transposed
    gemm_f16<128><<<dim3(24, 32), 256, 0, stream>>>(xf, Wf, ball,
                                                    nullptr, QKV, 3072, Vt);

    flash_f16<<<dim3(NQ / 128, 16, NB), 256, 0, stream>>>(QKV, Vt, AO);

    // o projection: fp32 out, TM=64 -> 512 blocks (2 blocks/CU)
    gemm_f16<64><<<dim3(8, 64), 256, 0, stream>>>(AO, Wf + 3072 * 1024,
                                                  ball + 3072, (float*)d_out, nullptr, 1024,
                                                  nullptr);
}